// Round 1
// baseline (442.140 us; speedup 1.0000x reference)
//
#include <hip/hip_runtime.h>
#include <math.h>

#define B 32
#define T 2048
#define D 1024
#define MEM 64
#define HID 512
#define NCH 32
#define TCH (T / NCH) /* 64 */

// workspace layout in floats
#define OFF_PART 0                     /* NCH*B*D = 1048576 */
#define OFF_XP (NCH * B * D)
#define OFF_H (OFF_XP + B * D)
#define OFF_LG (OFF_H + B * HID)
#define OFF_SIMS (OFF_LG + B * MEM)

#define ATT_BLKS B        /* 32  : one block per b, 4 waves x 16 m   */
#define MLP_BLKS (B * 4)  /* 128 : (b, jo), 4 waves x 32 j           */
#define SIMS_BLKS (B / 4) /* 8   : wave per b                        */

__device__ inline float waveReduceSum(float v) {
#pragma unroll
  for (int m = 32; m; m >>= 1) v += __shfl_xor(v, m, 64);
  return v;
}

// ---- 1. partial sums of x over T-chunks: part[ch][b][d] ----
// 1024 blocks = 4 blocks/CU = 16 waves/CU; unroll 8 -> 8 float4 loads in
// flight/thread. 256 MiB cold read (poison evicts L3) => HBM-BW-bound.
__global__ __launch_bounds__(256) void k_partial(const float* __restrict__ x,
                                                 float* __restrict__ part) {
  const int ch = blockIdx.x, b = blockIdx.y, d4 = threadIdx.x;
  const float4* xv =
      (const float4*)x + (((size_t)(b * T + ch * TCH) * D) >> 2) + d4;
  float4 acc = make_float4(0.f, 0.f, 0.f, 0.f);
#pragma unroll 8
  for (int t = 0; t < TCH; ++t) {
    float4 v = xv[(size_t)t * (D >> 2)];
    acc.x += v.x;
    acc.y += v.y;
    acc.z += v.z;
    acc.w += v.w;
  }
  ((float4*)(part + (size_t)(ch * B + b) * D))[d4] = acc;
}

// ---- 2. fused mean + projection: xp[b][e] = dot(mean_t x[b], xa_w[e]) + b[e]
// block = (b, eo): reduce partials for b into LDS once (4 KiB), then
// 4 waves x 32 outputs each against LDS. Weight row fetched exactly once
// per output (4 KiB) -> halves L2 traffic vs re-fetching xm per wave.
__global__ __launch_bounds__(256) void k_meanxp(const float* __restrict__ part,
                                                const float* __restrict__ w,
                                                const float* __restrict__ bias,
                                                float* __restrict__ xp) {
  const int b = blockIdx.x >> 3, eo = blockIdx.x & 7;
  const int tid = threadIdx.x, lane = tid & 63, wv = tid >> 6;
  __shared__ float s_xm[D];
  {
    float4 acc = make_float4(0.f, 0.f, 0.f, 0.f);
#pragma unroll 8
    for (int ch = 0; ch < NCH; ++ch) {
      float4 v = ((const float4*)(part + (size_t)(ch * B + b) * D))[tid];
      acc.x += v.x;
      acc.y += v.y;
      acc.z += v.z;
      acc.w += v.w;
    }
    const float s = 1.0f / (float)T;
    acc.x *= s;
    acc.y *= s;
    acc.z *= s;
    acc.w *= s;
    ((float4*)s_xm)[tid] = acc;
  }
  __syncthreads();
  const float4* s4 = (const float4*)s_xm;
#pragma unroll 2
  for (int i = 0; i < 32; ++i) {
    const int e = eo * 128 + wv * 32 + i;
    const float4* w4 = (const float4*)(w + (size_t)e * D);
    float acc = 0.f;
#pragma unroll
    for (int j = 0; j < 4; ++j) {
      float4 wvv = w4[j * 64 + lane];
      float4 av = s4[j * 64 + lane];
      acc += av.x * wvv.x + av.y * wvv.y + av.z * wvv.z + av.w * wvv.w;
    }
    acc = waveReduceSum(acc);
    if (lane == 0) xp[(size_t)b * D + e] = acc + bias[e];
  }
}

// ---- 3. fused: att logits [0,32) + MLP1/SiLU [32,160) + cos-sims [160,168)
// att/MLP branches stage xp[b] in LDS once per block; att hoists ||xp||^2
// out of the per-m loop (2 reduces/output instead of 3).
__global__ __launch_bounds__(256) void k_fused(
    const float* __restrict__ xp, const float* __restrict__ key,
    float* __restrict__ logit, const float* __restrict__ w1,
    const float* __restrict__ b1, float* __restrict__ h,
    const float* __restrict__ mk0, const float* __restrict__ mk1,
    float* __restrict__ sims) {
  const int tid = threadIdx.x, lane = tid & 63, wv = tid >> 6;
  __shared__ float s_xp[D];
  if (blockIdx.x < ATT_BLKS) {
    const int b = blockIdx.x;
    ((float4*)s_xp)[tid] = ((const float4*)(xp + (size_t)b * D))[tid];
    __syncthreads();
    const float4* s4 = (const float4*)s_xp;
    float x2 = 0.f;
#pragma unroll
    for (int j = 0; j < 4; ++j) {
      float4 av = s4[j * 64 + lane];
      x2 += av.x * av.x + av.y * av.y + av.z * av.z + av.w * av.w;
    }
    x2 = waveReduceSum(x2);
    const float xn = fmaxf(sqrtf(x2), 1e-12f);
#pragma unroll 2
    for (int i = 0; i < 16; ++i) {
      const int m = wv * 16 + i;
      const float4* k4 = (const float4*)(key + (size_t)m * D);
      float dot = 0.f, k2 = 0.f;
#pragma unroll
      for (int j = 0; j < 4; ++j) {
        float4 kv = k4[j * 64 + lane];
        float4 av = s4[j * 64 + lane];
        dot += av.x * kv.x + av.y * kv.y + av.z * kv.z + av.w * kv.w;
        k2 += kv.x * kv.x + kv.y * kv.y + kv.z * kv.z + kv.w * kv.w;
      }
      dot = waveReduceSum(dot);
      k2 = waveReduceSum(k2);
      if (lane == 0)
        logit[b * MEM + m] = dot / (xn * fmaxf(sqrtf(k2), 1e-12f) * 32.0f);
    }
  } else if (blockIdx.x < ATT_BLKS + MLP_BLKS) {
    const int p = blockIdx.x - ATT_BLKS;
    const int b = p >> 2, jo = p & 3;
    ((float4*)s_xp)[tid] = ((const float4*)(xp + (size_t)b * D))[tid];
    __syncthreads();
    const float4* s4 = (const float4*)s_xp;
#pragma unroll 2
    for (int i = 0; i < 32; ++i) {
      const int j = jo * 128 + wv * 32 + i;
      const float4* w4 = (const float4*)(w1 + (size_t)j * D);
      float acc = 0.f;
#pragma unroll
      for (int q = 0; q < 4; ++q) {
        float4 wvv = w4[q * 64 + lane];
        float4 av = s4[q * 64 + lane];
        acc += av.x * wvv.x + av.y * wvv.y + av.z * wvv.z + av.w * wvv.w;
      }
      acc = waveReduceSum(acc);
      if (lane == 0) {
        float z = acc + b1[j];
        h[(size_t)b * HID + j] = z / (1.0f + expf(-z)); // silu
      }
    }
  } else {
    // cosine sims: wave per b, vectorized
    const int b = (blockIdx.x - ATT_BLKS - MLP_BLKS) * 4 + wv;
    const float4* a4 = (const float4*)(xp + (size_t)b * D);
    const float4* m04 = (const float4*)mk0;
    const float4* m14 = (const float4*)mk1;
    float xx = 0.f, d0 = 0.f, d1 = 0.f, n0 = 0.f, n1 = 0.f;
#pragma unroll
    for (int j = 0; j < 4; ++j) {
      float4 av = a4[j * 64 + lane];
      float4 a0 = m04[j * 64 + lane];
      float4 a1 = m14[j * 64 + lane];
      xx += av.x * av.x + av.y * av.y + av.z * av.z + av.w * av.w;
      d0 += av.x * a0.x + av.y * a0.y + av.z * a0.z + av.w * a0.w;
      d1 += av.x * a1.x + av.y * a1.y + av.z * a1.z + av.w * a1.w;
      n0 += a0.x * a0.x + a0.y * a0.y + a0.z * a0.z + a0.w * a0.w;
      n1 += a1.x * a1.x + a1.y * a1.y + a1.z * a1.z + a1.w * a1.w;
    }
    xx = waveReduceSum(xx);
    d0 = waveReduceSum(d0);
    d1 = waveReduceSum(d1);
    n0 = waveReduceSum(n0);
    n1 = waveReduceSum(n1);
    if (lane == 0) {
      float xn = sqrtf(xx);
      sims[b * 2 + 0] = d0 / fmaxf(xn * sqrtf(n0), 1e-8f);
      sims[b * 2 + 1] = d1 / fmaxf(xn * sqrtf(n1), 1e-8f);
    }
  }
}

// ---- 4. softmax(64)+att@val, h@w2, concat gate, change-detector scalar ----
__global__ __launch_bounds__(256) void k_final(
    const float* __restrict__ h, const float* __restrict__ w2,
    const float* __restrict__ b2, const float* __restrict__ logit,
    const float* __restrict__ val, const float* __restrict__ cw,
    const float* __restrict__ cb, const float* __restrict__ sims,
    const float* __restrict__ thr, float* __restrict__ out) {
  const int b = blockIdx.x, tid = threadIdx.x, lane = tid & 63, wv = tid >> 6;
  __shared__ float s_red[4];
  __shared__ float s_mem;
  float acc = h[(size_t)b * HID + tid] * w2[tid] +
              h[(size_t)b * HID + 256 + tid] * w2[256 + tid];
  acc = waveReduceSum(acc);
  if (lane == 0) s_red[wv] = acc;
  if (wv == 0) { // wave 0 = 64 lanes = MEM
    float l = logit[b * MEM + lane];
    float mx = l;
#pragma unroll
    for (int m = 32; m; m >>= 1) mx = fmaxf(mx, __shfl_xor(mx, m, 64));
    float ex = expf(l - mx);
    float sm = waveReduceSum(ex);
    float mv = waveReduceSum((ex / sm) * val[lane]);
    if (lane == 0) s_mem = mv;
  }
  __syncthreads();
  if (tid == 0) {
    float mlp = s_red[0] + s_red[1] + s_red[2] + s_red[3] + b2[0];
    out[B + b] = cw[0] * s_mem + cw[1] * mlp + cb[0];
    int best = (sims[b * 2 + 1] > sims[b * 2 + 0]) ? 1 : 0;
    int changed;
    if (b == 0) {
      changed = 1;
    } else {
      int prev = (sims[(b - 1) * 2 + 1] > sims[(b - 1) * 2 + 0]) ? 1 : 0;
      changed = (best != prev);
    }
    out[b] = ((changed ? 1.0f : 0.0f) > thr[0]) ? 1.0f : 0.0f;
  }
}

extern "C" void kernel_launch(void* const* d_in, const int* in_sizes, int n_in,
                              void* d_out, int out_size, void* d_ws,
                              size_t ws_size, hipStream_t stream) {
  const float* x = (const float*)d_in[0];
  const float* mk0 = (const float*)d_in[1];
  const float* mk1 = (const float*)d_in[2];
  const float* key = (const float*)d_in[3];
  const float* val = (const float*)d_in[4];
  const float* w1 = (const float*)d_in[5];
  const float* b1 = (const float*)d_in[6];
  const float* w2 = (const float*)d_in[7];
  const float* b2 = (const float*)d_in[8];
  const float* cw = (const float*)d_in[9];
  const float* cb = (const float*)d_in[10];
  const float* xaw = (const float*)d_in[11];
  const float* xab = (const float*)d_in[12];
  const float* thr = (const float*)d_in[13];
  float* out = (float*)d_out;
  float* ws = (float*)d_ws;

  float* part = ws + OFF_PART;
  float* xp = ws + OFF_XP;
  float* h = ws + OFF_H;
  float* lg = ws + OFF_LG;
  float* sims = ws + OFF_SIMS;

  k_partial<<<dim3(NCH, B), 256, 0, stream>>>(x, part);
  k_meanxp<<<B * 8, 256, 0, stream>>>(part, xaw, xab, xp);
  k_fused<<<ATT_BLKS + MLP_BLKS + SIMS_BLKS, 256, 0, stream>>>(
      xp, key, lg, w1, b1, h, mk0, mk1, sims);
  k_final<<<B, 256, 0, stream>>>(h, w2, b2, lg, val, cw, cb, sims, thr, out);
}

// Round 2
// 406.878 us; speedup vs baseline: 1.0867x; 1.0867x over previous
//
#include <hip/hip_runtime.h>
#include <math.h>

#define B 32
#define T 2048
#define D 1024
#define MEM 64
#define HID 512
#define NCH 16
#define TCH (T / NCH) /* 128 */

// workspace layout in floats
#define OFF_PART 0                 /* NCH*B*D = 524288 */
#define OFF_XM (NCH * B * D)
#define OFF_XP (OFF_XM + B * D)
#define OFF_H (OFF_XP + B * D)
#define OFF_LG (OFF_H + B * HID)
#define OFF_SIMS (OFF_LG + B * MEM)

#define ATT_BLKS ((B * MEM) / 4)   /* 512 */
#define MLP_BLKS ((B * HID) / 4)   /* 4096 */
#define STATS_BLKS (B / 4)         /* 8 */

__device__ inline float waveReduceSum(float v) {
#pragma unroll
  for (int m = 32; m; m >>= 1) v += __shfl_xor(v, m, 64);
  return v;
}

// ---- 1. partial sums of x over T-chunks: part[ch][b][d] ----
// 512 blocks = 8 waves/CU; unroll 16 -> 16 float4 loads in flight/thread.
// Streaming read of 256 MiB (poison-cold) => HBM-BW-bound (~40 us floor).
__global__ __launch_bounds__(256) void k_partial(const float* __restrict__ x,
                                                 float* __restrict__ part) {
  const int ch = blockIdx.x, b = blockIdx.y, d4 = threadIdx.x;
  const float4* xv =
      (const float4*)x + (((size_t)(b * T + ch * TCH) * D) >> 2) + d4;
  float4 acc = make_float4(0.f, 0.f, 0.f, 0.f);
#pragma unroll 16
  for (int t = 0; t < TCH; ++t) {
    float4 v = xv[(size_t)t * (D >> 2)];
    acc.x += v.x;
    acc.y += v.y;
    acc.z += v.z;
    acc.w += v.w;
  }
  ((float4*)(part + (size_t)(ch * B + b) * D))[d4] = acc;
}

// ---- 2. reduce partials -> mean xm[b][d] ----
__global__ __launch_bounds__(256) void k_mean(const float* __restrict__ part,
                                              float* __restrict__ xm) {
  const int b = blockIdx.x, d4 = threadIdx.x;
  float4 acc = make_float4(0.f, 0.f, 0.f, 0.f);
#pragma unroll 8
  for (int ch = 0; ch < NCH; ++ch) {
    float4 v = ((const float4*)(part + (size_t)(ch * B + b) * D))[d4];
    acc.x += v.x;
    acc.y += v.y;
    acc.z += v.z;
    acc.w += v.w;
  }
  const float s = 1.0f / (float)T;
  acc.x *= s;
  acc.y *= s;
  acc.z *= s;
  acc.w *= s;
  ((float4*)(xm + (size_t)b * D))[d4] = acc;
}

// ---- 3. xp[b][e] = dot(xm[b], xa_w[e]) + xa_b[e]  (wave per output) ----
// Wave-per-output is deliberate: weights are poison-cold each iteration;
// 32768 waves x 4 independent loads keeps thousands of HBM misses in
// flight (BW-bound). Serializing rows per wave costs +10us (R1 lesson).
__global__ __launch_bounds__(256) void k_xp(const float* __restrict__ xm,
                                            const float* __restrict__ w,
                                            const float* __restrict__ bias,
                                            float* __restrict__ xp) {
  const int tid = threadIdx.x, lane = tid & 63, wv = tid >> 6;
  const int p = blockIdx.x * 4 + wv;
  const int b = p >> 10, e = p & 1023;
  const float4* a4 = (const float4*)(xm + (size_t)b * D);
  const float4* w4 = (const float4*)(w + (size_t)e * D);
  float acc = 0.f;
#pragma unroll
  for (int j = 0; j < 4; ++j) {
    float4 av = a4[j * 64 + lane];
    float4 wvv = w4[j * 64 + lane];
    acc += av.x * wvv.x + av.y * wvv.y + av.z * wvv.z + av.w * wvv.w;
  }
  acc = waveReduceSum(acc);
  if (lane == 0) xp[(size_t)b * D + e] = acc + bias[e];
}

// ---- 4. fused: att logits [0,512) + MLP1/SiLU [512,4608) + cos-sims [4608,4616) ----
__global__ __launch_bounds__(256) void k_fused(
    const float* __restrict__ xp, const float* __restrict__ key,
    float* __restrict__ logit, const float* __restrict__ w1,
    const float* __restrict__ b1, float* __restrict__ h,
    const float* __restrict__ mk0, const float* __restrict__ mk1,
    float* __restrict__ sims) {
  const int tid = threadIdx.x, lane = tid & 63, wv = tid >> 6;
  if (blockIdx.x < ATT_BLKS) {
    // attention logits: wave per (b,m); ||xp|| computed inline (row already loaded)
    const int p = blockIdx.x * 4 + wv;
    const int b = p >> 6, m = p & 63;
    const float4* a4 = (const float4*)(xp + (size_t)b * D);
    const float4* k4 = (const float4*)(key + (size_t)m * D);
    float dot = 0.f, k2 = 0.f, x2 = 0.f;
#pragma unroll
    for (int j = 0; j < 4; ++j) {
      float4 av = a4[j * 64 + lane];
      float4 kv = k4[j * 64 + lane];
      dot += av.x * kv.x + av.y * kv.y + av.z * kv.z + av.w * kv.w;
      k2 += kv.x * kv.x + kv.y * kv.y + kv.z * kv.z + kv.w * kv.w;
      x2 += av.x * av.x + av.y * av.y + av.z * av.z + av.w * av.w;
    }
    dot = waveReduceSum(dot);
    k2 = waveReduceSum(k2);
    x2 = waveReduceSum(x2);
    if (lane == 0) {
      float denom =
          fmaxf(sqrtf(x2), 1e-12f) * fmaxf(sqrtf(k2), 1e-12f) * 32.0f;
      logit[b * MEM + m] = dot / denom;
    }
  } else if (blockIdx.x < ATT_BLKS + MLP_BLKS) {
    // MLP layer 1 + SiLU: wave per (b,j)
    const int p = (blockIdx.x - ATT_BLKS) * 4 + wv;
    const int b = p >> 9, j = p & 511;
    const float4* a4 = (const float4*)(xp + (size_t)b * D);
    const float4* w4 = (const float4*)(w1 + (size_t)j * D);
    float acc = 0.f;
#pragma unroll
    for (int q = 0; q < 4; ++q) {
      float4 av = a4[q * 64 + lane];
      float4 wvv = w4[q * 64 + lane];
      acc += av.x * wvv.x + av.y * wvv.y + av.z * wvv.z + av.w * wvv.w;
    }
    acc = waveReduceSum(acc);
    if (lane == 0) {
      float z = acc + b1[j];
      h[(size_t)b * HID + j] = z / (1.0f + expf(-z)); // silu
    }
  } else {
    // cosine sims: wave per b
    const int b = (blockIdx.x - ATT_BLKS - MLP_BLKS) * 4 + wv;
    float xx = 0.f, d0 = 0.f, d1 = 0.f, n0 = 0.f, n1 = 0.f;
#pragma unroll
    for (int k = 0; k < 16; ++k) {
      int d = lane + k * 64;
      float v = xp[(size_t)b * D + d];
      float a = mk0[d];
      float c = mk1[d];
      xx += v * v;
      d0 += v * a;
      d1 += v * c;
      n0 += a * a;
      n1 += c * c;
    }
    xx = waveReduceSum(xx);
    d0 = waveReduceSum(d0);
    d1 = waveReduceSum(d1);
    n0 = waveReduceSum(n0);
    n1 = waveReduceSum(n1);
    if (lane == 0) {
      float xn = sqrtf(xx);
      sims[b * 2 + 0] = d0 / fmaxf(xn * sqrtf(n0), 1e-8f);
      sims[b * 2 + 1] = d1 / fmaxf(xn * sqrtf(n1), 1e-8f);
    }
  }
}

// ---- 5. softmax(64)+att@val, h@w2, concat gate, change-detector scalar ----
__global__ __launch_bounds__(256) void k_final(
    const float* __restrict__ h, const float* __restrict__ w2,
    const float* __restrict__ b2, const float* __restrict__ logit,
    const float* __restrict__ val, const float* __restrict__ cw,
    const float* __restrict__ cb, const float* __restrict__ sims,
    const float* __restrict__ thr, float* __restrict__ out) {
  const int b = blockIdx.x, tid = threadIdx.x, lane = tid & 63, wv = tid >> 6;
  __shared__ float s_red[4];
  __shared__ float s_mem;
  float acc = h[(size_t)b * HID + tid] * w2[tid] +
              h[(size_t)b * HID + 256 + tid] * w2[256 + tid];
  acc = waveReduceSum(acc);
  if (lane == 0) s_red[wv] = acc;
  if (wv == 0) { // wave 0 = 64 lanes = MEM
    float l = logit[b * MEM + lane];
    float mx = l;
#pragma unroll
    for (int m = 32; m; m >>= 1) mx = fmaxf(mx, __shfl_xor(mx, m, 64));
    float ex = expf(l - mx);
    float sm = waveReduceSum(ex);
    float mv = waveReduceSum((ex / sm) * val[lane]);
    if (lane == 0) s_mem = mv;
  }
  __syncthreads();
  if (tid == 0) {
    float mlp = s_red[0] + s_red[1] + s_red[2] + s_red[3] + b2[0];
    out[B + b] = cw[0] * s_mem + cw[1] * mlp + cb[0];
    int best = (sims[b * 2 + 1] > sims[b * 2 + 0]) ? 1 : 0;
    int changed;
    if (b == 0) {
      changed = 1;
    } else {
      int prev = (sims[(b - 1) * 2 + 1] > sims[(b - 1) * 2 + 0]) ? 1 : 0;
      changed = (best != prev);
    }
    out[b] = ((changed ? 1.0f : 0.0f) > thr[0]) ? 1.0f : 0.0f;
  }
}

extern "C" void kernel_launch(void* const* d_in, const int* in_sizes, int n_in,
                              void* d_out, int out_size, void* d_ws,
                              size_t ws_size, hipStream_t stream) {
  const float* x = (const float*)d_in[0];
  const float* mk0 = (const float*)d_in[1];
  const float* mk1 = (const float*)d_in[2];
  const float* key = (const float*)d_in[3];
  const float* val = (const float*)d_in[4];
  const float* w1 = (const float*)d_in[5];
  const float* b1 = (const float*)d_in[6];
  const float* w2 = (const float*)d_in[7];
  const float* b2 = (const float*)d_in[8];
  const float* cw = (const float*)d_in[9];
  const float* cb = (const float*)d_in[10];
  const float* xaw = (const float*)d_in[11];
  const float* xab = (const float*)d_in[12];
  const float* thr = (const float*)d_in[13];
  float* out = (float*)d_out;
  float* ws = (float*)d_ws;

  float* part = ws + OFF_PART;
  float* xm = ws + OFF_XM;
  float* xp = ws + OFF_XP;
  float* h = ws + OFF_H;
  float* lg = ws + OFF_LG;
  float* sims = ws + OFF_SIMS;

  k_partial<<<dim3(NCH, B), 256, 0, stream>>>(x, part);
  k_mean<<<B, 256, 0, stream>>>(part, xm);
  k_xp<<<(B * D) / 4, 256, 0, stream>>>(xm, xaw, xab, xp);
  k_fused<<<ATT_BLKS + MLP_BLKS + STATS_BLKS, 256, 0, stream>>>(
      xp, key, lg, w1, b1, h, mk0, mk1, sims);
  k_final<<<B, 256, 0, stream>>>(h, w2, b2, lg, val, cw, cb, sims, thr, out);
}